// Round 2
// baseline (87.468 us; speedup 1.0000x reference)
//
#include <hip/hip_runtime.h>
#include <math.h>

#define B 64
#define F 128
#define T 64
#define D 256

// Single fused kernel: one block per batch b.
//
// Algebraic collapse of the reference (sT is never materialized):
//   A[t] = sum_d wconv[t,d]*w1[t,d],  C[t] = sum_d bconv[t,d]*w1[t,d]
//   vatt[b,t,f]   = sigmoid(x[b,f,t]*A[t] + C[t] + b1[t,f])
//   S1[b,t] = sum_f vatt*x,  S0[b,t] = sum_f vatt
//   P[t] = sum_d wconv[t,d]*w2[d],   Q[t] = sum_d bconv[t,d]*w2[d]
//   tatt[b,t] = sigmoid(S1*P + S0*Q + b2[t])
//   out1[b,d] = sum_t tatt*(wconv[t,d]*S1 + bconv[t,d]*S0)
//   out2[b,f,t] = vatt[b,t,f]*tatt[b,t]
__global__ __launch_bounds__(256) void fused_kernel(
    const float* __restrict__ x,
    const float* __restrict__ wconv, const float* __restrict__ bconv,
    const float* __restrict__ w1, const float* __restrict__ b1,
    const float* __restrict__ w2, const float* __restrict__ b2,
    float* __restrict__ out1, float* __restrict__ out2) {

    __shared__ float vatt_s[F * T];          // [f][t], 32 KB
    __shared__ float b1_s[F * (T + 1)];      // [f][t], +1 pad
    __shared__ float As[T], Cs[T], Ps[T], Qs[T];
    __shared__ float s0red[4 * T], s1red[4 * T];
    __shared__ float s0_s[T], s1_s[T], tatt_s[T];

    const int b = blockIdx.x;
    const int tid = threadIdx.x;
    const int w = tid >> 6;      // wave id 0..3
    const int lane = tid & 63;   // == t in phase 1

    // Phase 0a: stage b1 [T,F] -> b1_s transposed [f][t]
    for (int lin = tid; lin < T * F; lin += 256) {
        const int t = lin >> 7;        // / F
        const int f = lin & (F - 1);
        b1_s[f * (T + 1) + t] = b1[lin];
    }

    // Phase 0b: per-block A,C,P,Q (weights are L2-resident, 192 KB/block).
    // 4 lanes per t: lane sub-quarter covers 64 consecutive d via 16 float4.
    {
        const int t = tid >> 2;        // 0..63
        const int sub = tid & 3;       // which quarter of D
        const float4* wc4 = reinterpret_cast<const float4*>(wconv + t * D + sub * 64);
        const float4* bc4 = reinterpret_cast<const float4*>(bconv + t * D + sub * 64);
        const float4* w14 = reinterpret_cast<const float4*>(w1 + t * D + sub * 64);
        const float4* w24 = reinterpret_cast<const float4*>(w2 + sub * 64);
        float a = 0.f, c = 0.f, p = 0.f, q = 0.f;
        #pragma unroll
        for (int i = 0; i < 16; ++i) {
            const float4 wcv = wc4[i];
            const float4 bcv = bc4[i];
            const float4 w1v = w14[i];
            const float4 w2v = w24[i];
            a += wcv.x*w1v.x + wcv.y*w1v.y + wcv.z*w1v.z + wcv.w*w1v.w;
            c += bcv.x*w1v.x + bcv.y*w1v.y + bcv.z*w1v.z + bcv.w*w1v.w;
            p += wcv.x*w2v.x + wcv.y*w2v.y + wcv.z*w2v.z + wcv.w*w2v.w;
            q += bcv.x*w2v.x + bcv.y*w2v.y + bcv.z*w2v.z + bcv.w*w2v.w;
        }
        // reduce across the 4 sub-lanes (same wave, lanes differ in bits 0-1)
        a += __shfl_xor(a, 1); a += __shfl_xor(a, 2);
        c += __shfl_xor(c, 1); c += __shfl_xor(c, 2);
        p += __shfl_xor(p, 1); p += __shfl_xor(p, 2);
        q += __shfl_xor(q, 1); q += __shfl_xor(q, 2);
        if (sub == 0) { As[t] = a; Cs[t] = c; Ps[t] = p; Qs[t] = q; }
    }
    __syncthreads();

    const float At = As[lane];
    const float Ct = Cs[lane];
    const float* xb = x + b * F * T;

    // Phase 1: vatt + per-wave partial S0/S1. lane = t so x loads are coalesced.
    float s0 = 0.f, s1 = 0.f;
    for (int f = w; f < F; f += 4) {
        const float xv = xb[f * T + lane];
        const float z = xv * At + Ct + b1_s[f * (T + 1) + lane];
        const float v = 1.0f / (1.0f + __expf(-z));
        vatt_s[f * T + lane] = v;
        s0 += v;
        s1 += v * xv;
    }
    s0red[w * T + lane] = s0;
    s1red[w * T + lane] = s1;
    __syncthreads();

    // Phase 2: cross-wave reduce + temporal attention (t = tid for tid < 64)
    if (tid < T) {
        const float S0 = s0red[tid] + s0red[T + tid] + s0red[2 * T + tid] + s0red[3 * T + tid];
        const float S1 = s1red[tid] + s1red[T + tid] + s1red[2 * T + tid] + s1red[3 * T + tid];
        const float z = S1 * Ps[tid] + S0 * Qs[tid] + b2[tid];
        const float ta = 1.0f / (1.0f + __expf(-z));
        s0_s[tid] = S0;
        s1_s[tid] = S1;
        tatt_s[tid] = ta;
    }
    __syncthreads();

    // Phase 3a: out1[b,d] = sum_t tatt*(wconv[t,d]*S1 + bconv[t,d]*S0); d = tid
    float acc = 0.f;
    #pragma unroll 8
    for (int t = 0; t < T; ++t) {
        acc += tatt_s[t] * (wconv[t * D + tid] * s1_s[t] + bconv[t * D + tid] * s0_s[t]);
    }
    out1[b * D + tid] = acc;

    // Phase 3b: out2[b,f,t] = vatt[b,t,f] * tatt[b,t] (coalesced writes)
    float* o2 = out2 + b * F * T;
    for (int lin = tid; lin < F * T; lin += 256) {
        o2[lin] = vatt_s[lin] * tatt_s[lin & (T - 1)];
    }
}

extern "C" void kernel_launch(void* const* d_in, const int* in_sizes, int n_in,
                              void* d_out, int out_size, void* d_ws, size_t ws_size,
                              hipStream_t stream) {
    const float* x     = (const float*)d_in[0];
    const float* wconv = (const float*)d_in[1];
    const float* bconv = (const float*)d_in[2];
    const float* w1    = (const float*)d_in[3];
    const float* b1    = (const float*)d_in[4];
    const float* w2    = (const float*)d_in[5];
    const float* b2    = (const float*)d_in[6];
    float* out = (float*)d_out;             // [B,D] then [B,F,T], concatenated

    fused_kernel<<<B, 256, 0, stream>>>(x, wconv, bconv, w1, b1, w2, b2,
                                        out, out + B * D);
}

// Round 3
// 74.252 us; speedup vs baseline: 1.1780x; 1.1780x over previous
//
#include <hip/hip_runtime.h>
#include <math.h>

#define B 64
#define F 128
#define T 64
#define D 256

// Kernel 1: per-t scalar reductions over D (weights read ONCE, not per-block).
// A[t] = sum_d wconv[t,d]*w1[t,d]   -> ws[0..63]
// C[t] = sum_d bconv[t,d]*w1[t,d]   -> ws[64..127]
// P[t] = sum_d wconv[t,d]*w2[d]     -> ws[128..191]
// Q[t] = sum_d bconv[t,d]*w2[d]     -> ws[192..255]
__global__ __launch_bounds__(64) void precompute_kernel(
    const float* __restrict__ wconv, const float* __restrict__ bconv,
    const float* __restrict__ w1, const float* __restrict__ w2,
    float* __restrict__ ws) {
    const int t = blockIdx.x;
    const int lane = threadIdx.x;           // 0..63, 4 d's per lane
    const int base = t * D + lane * 4;
    const float4 wc  = *reinterpret_cast<const float4*>(wconv + base);
    const float4 bc  = *reinterpret_cast<const float4*>(bconv + base);
    const float4 w1v = *reinterpret_cast<const float4*>(w1 + base);
    const float4 w2v = *reinterpret_cast<const float4*>(w2 + lane * 4);
    float a = wc.x*w1v.x + wc.y*w1v.y + wc.z*w1v.z + wc.w*w1v.w;
    float c = bc.x*w1v.x + bc.y*w1v.y + bc.z*w1v.z + bc.w*w1v.w;
    float p = wc.x*w2v.x + wc.y*w2v.y + wc.z*w2v.z + wc.w*w2v.w;
    float q = bc.x*w2v.x + bc.y*w2v.y + bc.z*w2v.z + bc.w*w2v.w;
    #pragma unroll
    for (int off = 32; off > 0; off >>= 1) {   // wave64 reduce
        a += __shfl_down(a, off);
        c += __shfl_down(c, off);
        p += __shfl_down(p, off);
        q += __shfl_down(q, off);
    }
    if (lane == 0) {
        ws[t]         = a;
        ws[T + t]     = c;
        ws[2 * T + t] = p;
        ws[3 * T + t] = q;
    }
}

// Kernel 2: one block per batch b.
__global__ __launch_bounds__(256) void main_kernel(
    const float* __restrict__ x,
    const float* __restrict__ wconv, const float* __restrict__ bconv,
    const float* __restrict__ b1, const float* __restrict__ b2,
    const float* __restrict__ ws,
    float* __restrict__ out1, float* __restrict__ out2) {

    __shared__ float vatt_s[F * T];          // [f][t], 32 KB
    __shared__ float b1_s[F * (T + 1)];      // [f][t], +1 pad (2-way write aliasing = free)
    __shared__ float s0red[4 * T], s1red[4 * T];
    __shared__ float s0_s[T], s1_s[T], tatt_s[T];

    const int b = blockIdx.x;
    const int tid = threadIdx.x;
    const int w = tid >> 6;      // wave id 0..3
    const int lane = tid & 63;   // == t in phase 1

    const float* xb = x + b * F * T;

    // Hoist ALL x loads for this thread above the barrier: 32 independent
    // global loads in flight while b1 staging proceeds. f = w + 4*i.
    float xv[32];
    #pragma unroll
    for (int i = 0; i < 32; ++i) {
        xv[i] = xb[(w + 4 * i) * T + lane];
    }

    // Stage b1 [T,F] -> b1_s transposed [f][t]
    for (int lin = tid; lin < T * F; lin += 256) {
        const int t = lin >> 7;        // / F
        const int f = lin & (F - 1);
        b1_s[f * (T + 1) + t] = b1[lin];
    }

    const float At = ws[lane];
    const float Ct = ws[T + lane];

    __syncthreads();

    // Phase 1: vatt + per-wave partial S0/S1 (pure VALU+LDS now).
    float s0 = 0.f, s1 = 0.f;
    #pragma unroll
    for (int i = 0; i < 32; ++i) {
        const int f = w + 4 * i;
        const float z = xv[i] * At + Ct + b1_s[f * (T + 1) + lane];
        const float v = 1.0f / (1.0f + __expf(-z));
        vatt_s[f * T + lane] = v;
        s0 += v;
        s1 += v * xv[i];
    }
    s0red[w * T + lane] = s0;
    s1red[w * T + lane] = s1;
    __syncthreads();

    // Phase 2: cross-wave reduce + temporal attention (t = tid for tid < 64)
    if (tid < T) {
        const float S0 = s0red[tid] + s0red[T + tid] + s0red[2 * T + tid] + s0red[3 * T + tid];
        const float S1 = s1red[tid] + s1red[T + tid] + s1red[2 * T + tid] + s1red[3 * T + tid];
        const float Pt = ws[2 * T + tid];
        const float Qt = ws[3 * T + tid];
        const float z = S1 * Pt + S0 * Qt + b2[tid];
        const float ta = 1.0f / (1.0f + __expf(-z));
        s0_s[tid] = S0;
        s1_s[tid] = S1;
        tatt_s[tid] = ta;
    }
    __syncthreads();

    // Phase 3a: out1[b,d] = sum_t tatt*(wconv[t,d]*S1 + bconv[t,d]*S0); d = tid
    float acc = 0.f;
    #pragma unroll 16
    for (int t = 0; t < T; ++t) {
        acc += tatt_s[t] * (wconv[t * D + tid] * s1_s[t] + bconv[t * D + tid] * s0_s[t]);
    }
    out1[b * D + tid] = acc;

    // Phase 3b: out2[b,f,t] = vatt[b,t,f] * tatt[b,t] (coalesced writes)
    float* o2 = out2 + b * F * T;
    for (int lin = tid; lin < F * T; lin += 256) {
        o2[lin] = vatt_s[lin] * tatt_s[lin & (T - 1)];
    }
}

extern "C" void kernel_launch(void* const* d_in, const int* in_sizes, int n_in,
                              void* d_out, int out_size, void* d_ws, size_t ws_size,
                              hipStream_t stream) {
    const float* x     = (const float*)d_in[0];
    const float* wconv = (const float*)d_in[1];
    const float* bconv = (const float*)d_in[2];
    const float* w1    = (const float*)d_in[3];
    const float* b1    = (const float*)d_in[4];
    const float* w2    = (const float*)d_in[5];
    const float* b2    = (const float*)d_in[6];
    float* out = (float*)d_out;             // [B,D] then [B,F,T], concatenated
    float* ws  = (float*)d_ws;              // 256 floats: A,C,P,Q

    precompute_kernel<<<T, 64, 0, stream>>>(wconv, bconv, w1, w2, ws);
    main_kernel<<<B, 256, 0, stream>>>(x, wconv, bconv, b1, b2, ws,
                                       out, out + B * D);
}